// Round 4
// baseline (28.983 us; speedup 1.0000x reference)
//
#include <hip/hip_runtime.h>

#define Nn 4096
#define NTRI 528              // 32*33/2 upper-tri 128x128 tiles
#define NBLK 2080             // 2*528 + 1024

typedef __attribute__((ext_vector_type(8))) short  short8v;
typedef __attribute__((ext_vector_type(4))) float  f32x4;

#define C_K   0.7213475204444817f   // log2(e)/mu, mu=2
#define C_2K  1.4426950408889634f   // 2*log2(e)/mu

__device__ __forceinline__ unsigned short f2bf(float f) {
  unsigned u = __float_as_uint(f);
  u += 0x7fffu + ((u >> 16) & 1u);   // round-to-nearest-even
  return (unsigned short)(u >> 16);
}

__device__ __forceinline__ void gload_lds16(const void* g, void* l) {
  __builtin_amdgcn_global_load_lds(
      (const __attribute__((address_space(1))) unsigned int*)g,
      (__attribute__((address_space(3))) unsigned int*)l, 16, 0, 0);
}

// ---- prep: bf16 cast + prescaled norms kn[row] = -K * ||row||^2 -------------
__global__ __launch_bounds__(256) void prep_kernel(const float* __restrict__ X,
                                                   const float* __restrict__ Y,
                                                   float* __restrict__ kn,
                                                   unsigned short* __restrict__ Xb,
                                                   unsigned short* __restrict__ Yb) {
  int wave = threadIdx.x >> 6;
  int lane = threadIdx.x & 63;
  int row = blockIdx.x * 4 + wave;            // 0..8191
  const float* src;
  unsigned short* dst;
  if (row < Nn) { src = X + (size_t)row * 128;        dst = Xb + (size_t)row * 128; }
  else          { src = Y + (size_t)(row - Nn) * 128; dst = Yb + (size_t)(row - Nn) * 128; }
  float2 v = reinterpret_cast<const float2*>(src)[lane];
  float s = v.x * v.x + v.y * v.y;
#pragma unroll
  for (int off = 32; off > 0; off >>= 1) s += __shfl_xor(s, off);
  ushort2 h;
  h.x = f2bf(v.x);
  h.y = f2bf(v.y);
  reinterpret_cast<ushort2*>(dst)[lane] = h;
  if (lane == 0) kn[row] = -C_K * s;
}

// ---- fused pairwise-exp-sum, ping-pong BK=32 ---------------------------------
// t < 528:        q=0 (XX), upper-tri tile (by<=bx), off-diag weight 2
// 528 <= t <1056: q=1 (YY), same
// t >= 1056:      q=2 (XY), full 32x32
//
// LDS: 2 buffers x (A 8KB + B 8KB) = 32KB. Per operand-chunk: 128 rows x 64B
// (k=32 bf16). Involution swizzle within each 8-row/512B group:
//   physical(rr,ss) of logical(r,s):  rr = r ^ ((r>>2)&1),  ss = s ^ (r&3)
// Applied on BOTH sides: inverse (= same) map on the per-lane global source for
// global_load_lds (linear LDS dest), and on the ds_read address. A wave's frag
// read covers every 16B slot of two 512B groups exactly once -> 2-way, free.
__global__ __launch_bounds__(256, 4) void mmd_main(const unsigned short* __restrict__ Xb,
                                                   const unsigned short* __restrict__ Yb,
                                                   const float* __restrict__ kn,
                                                   float* __restrict__ partials) {
  __shared__ __align__(16) char lds[32768];

  const int t = blockIdx.x;
  int q, bx, by;
  if (t < 2 * NTRI) {
    q = (t >= NTRI) ? 1 : 0;
    const int u = t - q * NTRI;
    int r = (int)((sqrtf(8.f * (float)u + 1.f) - 1.f) * 0.5f);
    while ((r + 1) * (r + 2) / 2 <= u) ++r;
    while (r * (r + 1) / 2 > u) --r;
    bx = r; by = u - r * (r + 1) / 2;          // by <= bx
  } else {
    q = 2;
    const int u = t - 2 * NTRI;
    by = u >> 5; bx = u & 31;
  }

  const unsigned short* Asrc = (q == 1) ? Yb : Xb;
  const unsigned short* Bsrc = (q == 0) ? Xb : Yb;
  const float* knA = (q == 1) ? kn + Nn : kn;
  const float* knB = (q == 0) ? kn : kn + Nn;
  const int R0 = by << 7, C0 = bx << 7;

  const int lane = threadIdx.x & 63;
  const int wv   = threadIdx.x >> 6;
  const int wr = wv >> 1, wc = wv & 1;    // 2x2 wave grid, 64x64 per wave
  const int lr = lane & 15, kq = lane >> 4;

  // ---- stage-side lane constants: invert the swizzle on the global source ----
  const int sg  = lane >> 5;               // which 8-row group of the 1KB segment
  const int srr = (lane >> 2) & 7;         // physical row-in-group this lane fills
  const int sss = lane & 3;                // physical 16B slot this lane fills
  const int sr  = srr ^ ((srr >> 2) & 1);  // logical row-in-group
  const int ssl = sss ^ (sr & 3);          // logical k-slot
  const int lrow  = sg * 8 + sr;           // logical row within 16-row segment
  const int skoff = ssl << 4;              // k-byte offset within 64B chunk-row

  const char* Ag = (const char*)Asrc + (((size_t)(R0 + (wv << 5) + lrow)) << 8) + skoff;
  const char* Bg = (const char*)Bsrc + (((size_t)(C0 + (wv << 5) + lrow)) << 8) + skoff;

  // ---- read-side lane constants ----------------------------------------------
  const int rL  = lr & 7;
  const int rrL = rL ^ ((rL >> 2) & 1);
  const int ssL = kq ^ (rL & 3);
  const int rdoff = ((lr >> 3) << 9) + (rrL << 6) + (ssL << 4);

  f32x4 acc[4][4];
#pragma unroll
  for (int m = 0; m < 4; ++m)
#pragma unroll
    for (int n = 0; n < 4; ++n)
      acc[m][n] = (f32x4){0.f, 0.f, 0.f, 0.f};

  // chunk ch (k-bytes [ch*64, ch*64+64)) into buffer b
#define STAGE(ch, b)                                                              \
  do {                                                                            \
    char* db = lds + (b) * 16384 + (wv << 11);                                    \
    gload_lds16(Ag + ((ch) << 6),        db);                                     \
    gload_lds16(Ag + ((ch) << 6) + 4096, db + 1024);                              \
    gload_lds16(Bg + ((ch) << 6),        db + 8192);                              \
    gload_lds16(Bg + ((ch) << 6) + 4096, db + 8192 + 1024);                       \
  } while (0)

#define COMPUTE(b)                                                                \
  do {                                                                            \
    short8v af[4], bf[4];                                                         \
    const char* ab = lds + (b) * 16384 + (wr << 12) + rdoff;                      \
    const char* bb = lds + (b) * 16384 + 8192 + (wc << 12) + rdoff;               \
    _Pragma("unroll") for (int m = 0; m < 4; ++m)                                 \
      af[m] = *reinterpret_cast<const short8v*>(ab + (m << 10));                  \
    _Pragma("unroll") for (int n = 0; n < 4; ++n)                                 \
      bf[n] = *reinterpret_cast<const short8v*>(bb + (n << 10));                  \
    _Pragma("unroll") for (int m = 0; m < 4; ++m)                                 \
      _Pragma("unroll") for (int n = 0; n < 4; ++n)                               \
        acc[m][n] = __builtin_amdgcn_mfma_f32_16x16x32_bf16(af[m], bf[n],         \
                                                            acc[m][n], 0, 0, 0); \
  } while (0)

  STAGE(0, 0);
  __syncthreads();                 // ch0 resident
  STAGE(1, 1); COMPUTE(0); __syncthreads();
  STAGE(2, 0); COMPUTE(1); __syncthreads();
  STAGE(3, 1); COMPUTE(0); __syncthreads();
  COMPUTE(1);

#undef STAGE
#undef COMPUTE

  // ---- epilogue: sum exp2(fma(s, 2K, knA[r]+knB[c])) --------------------------
  const bool diagblk = (q < 2) && (bx == by);
  float cy[4];
#pragma unroll
  for (int n = 0; n < 4; ++n) cy[n] = knB[C0 + (wc << 6) + (n << 4) + lr];

  float l0 = 0.f, l1 = 0.f, l2 = 0.f, l3 = 0.f;
#pragma unroll
  for (int m = 0; m < 4; ++m) {
    const int rbase = (wr << 6) + (m << 4) + (kq << 2);          // local row base
    const f32x4 ax = *reinterpret_cast<const f32x4*>(knA + R0 + rbase);
#pragma unroll
    for (int n = 0; n < 4; ++n) {
      const float e0 = __builtin_amdgcn_exp2f(fmaf(acc[m][n][0], C_2K, ax[0] + cy[n]));
      const float e1 = __builtin_amdgcn_exp2f(fmaf(acc[m][n][1], C_2K, ax[1] + cy[n]));
      const float e2 = __builtin_amdgcn_exp2f(fmaf(acc[m][n][2], C_2K, ax[2] + cy[n]));
      const float e3 = __builtin_amdgcn_exp2f(fmaf(acc[m][n][3], C_2K, ax[3] + cy[n]));
      if (diagblk) {
        const int cc = (wc << 6) + (n << 4) + lr;
        if (rbase + 0 != cc) l0 += e0;
        if (rbase + 1 != cc) l1 += e1;
        if (rbase + 2 != cc) l2 += e2;
        if (rbase + 3 != cc) l3 += e3;
      } else {
        l0 += e0; l1 += e1; l2 += e2; l3 += e3;
      }
    }
  }
  float local = (l0 + l1) + (l2 + l3);

#pragma unroll
  for (int off = 32; off > 0; off >>= 1) local += __shfl_xor(local, off);

  // red[] aliased onto buffer 0 (last read of buf0 was 2 barriers ago)
  float* red = reinterpret_cast<float*>(lds);
  if (lane == 0) red[wv] = local;
  __syncthreads();
  if (threadIdx.x == 0) {
    float s = (red[0] + red[1]) + (red[2] + red[3]);
    float w;
    if (q < 2) w = ((bx == by) ? 1.f : 2.f) * (1.0f / 16773120.0f);  // alpha
    else       w = -2.0f / 16777216.0f;                               // -2*beta
    partials[t] = s * w;
  }
}

// ---- deterministic final reduction ------------------------------------------
__global__ __launch_bounds__(256) void mmd_final(const float* __restrict__ partials,
                                                 float* __restrict__ out) {
  float v = 0.f;
  for (int i = threadIdx.x; i < NBLK; i += 256) v += partials[i];
#pragma unroll
  for (int off = 32; off > 0; off >>= 1) v += __shfl_xor(v, off);
  __shared__ float red[4];
  if ((threadIdx.x & 63) == 0) red[threadIdx.x >> 6] = v;
  __syncthreads();
  if (threadIdx.x == 0) {
    // analytic diagonal: n*(alpha1+alpha2) = 2/4095
    out[0] = ((red[0] + red[1]) + (red[2] + red[3])) + (float)(2.0 / 4095.0);
  }
}

extern "C" void kernel_launch(void* const* d_in, const int* in_sizes, int n_in,
                              void* d_out, int out_size, void* d_ws, size_t ws_size,
                              hipStream_t stream) {
  const float* X = (const float*)d_in[0];
  const float* Y = (const float*)d_in[1];
  float* kn       = (float*)d_ws;                       // 8192 floats (-K*norm^2)
  float* partials = kn + 8192;                          // 2080 floats
  unsigned short* Xb = (unsigned short*)(partials + 2080);
  unsigned short* Yb = Xb + (size_t)Nn * 128;
  float* out = (float*)d_out;

  hipLaunchKernelGGL(prep_kernel, dim3(2048), dim3(256), 0, stream, X, Y, kn, Xb, Yb);
  hipLaunchKernelGGL(mmd_main, dim3(NBLK), dim3(256), 0, stream, Xb, Yb, kn, partials);
  hipLaunchKernelGGL(mmd_final, dim3(1), dim3(256), 0, stream, partials, out);
}